// Round 1
// baseline (235.408 us; speedup 1.0000x reference)
//
#include <hip/hip_runtime.h>

#define MASK_VALF 1000000000000.0f

typedef __attribute__((ext_vector_type(8))) short s16x8;   // 8 bf16 (4 VGPRs)
typedef __attribute__((ext_vector_type(4))) float f32x4;   // MFMA acc

__device__ __forceinline__ short f2bf(float f) {
    union { float f; unsigned u; } v; v.f = f;
    unsigned r = (v.u + 0x7FFFu + ((v.u >> 16) & 1u)) >> 16;  // RNE
    return (short)(r & 0xFFFFu);
}

// async global->LDS, 16B per lane; lds pointer must be wave-uniform base.
#define GLOAD16(gp, lp) __builtin_amdgcn_global_load_lds( \
    (const __attribute__((address_space(1))) void*)(gp),  \
    (__attribute__((address_space(3))) void*)(lp), 16, 0, 0)

// ---------------- prep: enc f32 -> bf16 ----------------
__global__ void prep_enc(const float* __restrict__ enc, short* __restrict__ encb, int n4) {
    int i = blockIdx.x * blockDim.x + threadIdx.x;
    if (i < n4) {
        float4 v = ((const float4*)enc)[i];
        short4 o;
        o.x = f2bf(v.x); o.y = f2bf(v.y); o.z = f2bf(v.z); o.w = f2bf(v.w);
        ((short4*)encb)[i] = o;
    }
}

// ---------------- prep: W (768x1152) -> Wt (1152x768) bf16 ----------------
__global__ void transpose_w(const float* __restrict__ W, short* __restrict__ Wt) {
    __shared__ float tile[32][33];
    int n = blockIdx.x * 32 + threadIdx.x;
    int k = blockIdx.y * 32 + threadIdx.y;
    tile[threadIdx.y][threadIdx.x] = W[k * 1152 + n];
    __syncthreads();
    int n2 = blockIdx.x * 32 + threadIdx.y;
    int k2 = blockIdx.y * 32 + threadIdx.x;
    Wt[n2 * 768 + k2] = f2bf(tile[threadIdx.x][threadIdx.y]);
}

// ---------------- prep: rope sin/cos table [512][32] (cos, sin) ----------------
__global__ void sincos_tab(float2* __restrict__ sc) {
    int id = blockIdx.x * blockDim.x + threadIdx.x;  // 16384
    int pos = id >> 5, j = id & 31;
    float inv = powf(10000.0f, -2.0f * (float)j / 64.0f);
    float ang = (float)pos * inv;
    float s, c;
    sincosf(ang, &s, &c);
    sc[id] = make_float2(c, s);
}

// ---------------- GEMM1: (8192x768)bf16 @ Wt(1152x768)bf16 + bias, RoPE, -> qk bf16 ----------------
// qk layout: [bh=144][qk=2][s=512][d=64]
__global__ __launch_bounds__(256) void gemm1_rope(
    const short* __restrict__ A,    // 8192x768 bf16 row-major
    const short* __restrict__ Bt,   // 1152x768 bf16 row-major (W^T)
    const float* __restrict__ bias, // 1152
    const float2* __restrict__ sc,  // 512x32
    short* __restrict__ qk)
{
    __shared__ __align__(16) short As[128 * 32];
    __shared__ __align__(16) short Bs[128 * 32];
    const int t = threadIdx.x;
    const int w = t >> 6, lane = t & 63;
    const int lr = lane & 15, quad = lane >> 4;
    const int wm = w >> 1, wn = w & 1;
    const int m0 = blockIdx.y * 128;
    const int n0 = blockIdx.x * 128;

    f32x4 acc[4][4] = {};

    const short* gA = A  + (size_t)(m0 + (t >> 2)) * 768 + (t & 3) * 8;
    const short* gB = Bt + (size_t)(n0 + (t >> 2)) * 768 + (t & 3) * 8;
    short* lA0 = &As[w * 512];
    short* lA1 = &As[2048 + w * 512];
    short* lB0 = &Bs[w * 512];
    short* lB1 = &Bs[2048 + w * 512];

    for (int kt = 0; kt < 24; ++kt) {
        __syncthreads();
        GLOAD16(gA,            lA0);
        GLOAD16(gA + 64 * 768, lA1);
        GLOAD16(gB,            lB0);
        GLOAD16(gB + 64 * 768, lB1);
        gA += 32; gB += 32;
        __syncthreads();

        s16x8 af[4], bw[4];
#pragma unroll
        for (int i = 0; i < 4; ++i)
            af[i] = *(const s16x8*)&As[(wm * 64 + i * 16 + lr) * 32 + quad * 8];
#pragma unroll
        for (int j = 0; j < 4; ++j)
            bw[j] = *(const s16x8*)&Bs[(wn * 64 + j * 16 + lr) * 32 + quad * 8];
#pragma unroll
        for (int i = 0; i < 4; ++i)
#pragma unroll
            for (int j = 0; j < 4; ++j)
                acc[i][j] = __builtin_amdgcn_mfma_f32_16x16x32_bf16(af[i], bw[j], acc[i][j], 0, 0, 0);
    }

    // epilogue: bias + RoPE + scatter to qk
#pragma unroll
    for (int j = 0; j < 4; ++j) {
        const int colg = n0 + wn * 64 + j * 16 + lr;
        const float bv = bias[colg];
        const int tag = colg >> 7;          // 0..8
        const int qkf = (colg >> 6) & 1;    // 0=q, 1=k
        const int dd  = colg & 63;          // dim within head
        const int jj  = dd >> 1;            // rope freq index
        const int odd = colg & 1;
#pragma unroll
        for (int i = 0; i < 4; ++i) {
#pragma unroll
            for (int r = 0; r < 4; ++r) {
                const int rowg = m0 + wm * 64 + i * 16 + quad * 4 + r;
                const int bidx = rowg >> 9;
                const int pos  = rowg & 511;
                float v = acc[i][j][r] + bv;
                float p = __shfl_xor(v, 1, 64);          // partner column (col^1)
                float2 cs = sc[pos * 32 + jj];
                // even: x*cos - x_odd*sin ; odd: x*cos + x_even*sin
                float o = odd ? fmaf(v, cs.x, p * cs.y)
                              : fmaf(v, cs.x, -p * cs.y);
                qk[((((size_t)bidx * 9 + tag) * 2 + qkf) * 512 + pos) * 64 + dd] = f2bf(o);
            }
        }
    }
}

// ---------------- GEMM2: per (b,h): Q(512x64) @ K(512x64)^T, masks, *0.125, f32 out ----------------
__global__ __launch_bounds__(256) void gemm2_mask(
    const short* __restrict__ qk,
    const int* __restrict__ amask,   // (16,512) int32
    float* __restrict__ out)         // (16,9,512,512) f32
{
    __shared__ __align__(16) short Qs[128 * 64];
    __shared__ __align__(16) short Ks[128 * 64];
    const int t = threadIdx.x;
    const int w = t >> 6, lane = t & 63;
    const int lr = lane & 15, quad = lane >> 4;
    const int wm = w >> 1, wn = w & 1;
    const int bh = blockIdx.z;
    const int bidx = bh / 9;
    const int s0 = blockIdx.y * 128;
    const int t0 = blockIdx.x * 128;

    const short* qbase = qk + (size_t)bh * 2 * 512 * 64;
    const short* kbase = qbase + 512 * 64;

    const int row = t >> 3, col8 = (t & 7) * 8;
#pragma unroll
    for (int p = 0; p < 4; ++p) {
        GLOAD16(qbase + (size_t)(s0 + p * 32 + row) * 64 + col8, &Qs[p * 2048 + w * 512]);
        GLOAD16(kbase + (size_t)(t0 + p * 32 + row) * 64 + col8, &Ks[p * 2048 + w * 512]);
    }
    __syncthreads();

    f32x4 acc[4][4] = {};
#pragma unroll
    for (int kk = 0; kk < 64; kk += 32) {
        s16x8 af[4], bw[4];
#pragma unroll
        for (int i = 0; i < 4; ++i)
            af[i] = *(const s16x8*)&Qs[(wm * 64 + i * 16 + lr) * 64 + kk + quad * 8];
#pragma unroll
        for (int j = 0; j < 4; ++j)
            bw[j] = *(const s16x8*)&Ks[(wn * 64 + j * 16 + lr) * 64 + kk + quad * 8];
#pragma unroll
        for (int i = 0; i < 4; ++i)
#pragma unroll
            for (int j = 0; j < 4; ++j)
                acc[i][j] = __builtin_amdgcn_mfma_f32_16x16x32_bf16(af[i], bw[j], acc[i][j], 0, 0, 0);
    }

#pragma unroll
    for (int j = 0; j < 4; ++j) {
        const int tg = t0 + wn * 64 + j * 16 + lr;
        const float padf = (float)amask[bidx * 512 + tg];
        const float mk = (1.0f - padf) * MASK_VALF;
#pragma unroll
        for (int i = 0; i < 4; ++i) {
#pragma unroll
            for (int r = 0; r < 4; ++r) {
                const int sg = s0 + wm * 64 + i * 16 + quad * 4 + r;
                float v = acc[i][j][r] * padf - mk - (sg > tg ? MASK_VALF : 0.0f);
                out[((size_t)bh * 512 + sg) * 512 + tg] = v * 0.125f;
            }
        }
    }
}

extern "C" void kernel_launch(void* const* d_in, const int* in_sizes, int n_in,
                              void* d_out, int out_size, void* d_ws, size_t ws_size,
                              hipStream_t stream) {
    const float* enc   = (const float*)d_in[0];
    // d_in[1] = token_ids (unused by reference)
    const int*   amask = (const int*)d_in[2];
    const float* W     = (const float*)d_in[3];
    const float* bias  = (const float*)d_in[4];
    float* out = (float*)d_out;

    char* ws = (char*)d_ws;
    short*  encb = (short*)(ws);                 // 8192*768*2   = 12,582,912 B
    short*  wtb  = (short*)(ws + 12582912);      // 1152*768*2   =  1,769,472 B
    float2* sc   = (float2*)(ws + 14352384);     // 512*32*8     =    131,072 B
    short*  qk   = (short*)(ws + 14483456);      // 144*2*512*64*2 = 18,874,368 B

    prep_enc  <<<6144, 256, 0, stream>>>(enc, encb, 1572864);
    transpose_w<<<dim3(36, 24), dim3(32, 32), 0, stream>>>(W, wtb);
    sincos_tab<<<64, 256, 0, stream>>>(sc);
    gemm1_rope<<<dim3(9, 64), 256, 0, stream>>>(encb, wtb, bias, sc, qk);
    gemm2_mask<<<dim3(4, 4, 144), 256, 0, stream>>>(qk, amask, out);
}

// Round 2
// 225.935 us; speedup vs baseline: 1.0419x; 1.0419x over previous
//
#include <hip/hip_runtime.h>

#define MASK_VALF 1000000000000.0f

typedef __attribute__((ext_vector_type(8))) short s16x8;   // 8 bf16 (4 VGPRs)
typedef __attribute__((ext_vector_type(4))) float f32x4;   // MFMA acc

__device__ __forceinline__ unsigned f2bf_u(float f) {
    union { float f; unsigned u; } v; v.f = f;
    return (v.u + 0x7FFFu + ((v.u >> 16) & 1u)) >> 16;  // RNE, low 16 bits valid
}
__device__ __forceinline__ short f2bf(float f) { return (short)(f2bf_u(f) & 0xFFFFu); }

// async global->LDS, 16B per lane; lds pointer must be wave-uniform base.
#define GLOAD16(gp, lp) __builtin_amdgcn_global_load_lds( \
    (const __attribute__((address_space(1))) void*)(gp),  \
    (__attribute__((address_space(3))) void*)(lp), 16, 0, 0)

// ---------------- fused prep: enc->bf16 | W transpose->bf16 | sincos table ----------------
__global__ __launch_bounds__(256) void prep_all(
    const float* __restrict__ enc, short* __restrict__ encb,
    const float* __restrict__ W, short* __restrict__ wtb,
    float* __restrict__ scf)
{
    const int blk = blockIdx.x;
    const int t = threadIdx.x;
    if (blk < 6144) {
        // enc f32 -> bf16, 4 elements/thread
        int i = blk * 256 + t;
        float4 v = ((const float4*)enc)[i];
        short4 o;
        o.x = f2bf(v.x); o.y = f2bf(v.y); o.z = f2bf(v.z); o.w = f2bf(v.w);
        ((short4*)encb)[i] = o;
    } else if (blk < 7008) {
        // W (768 x 1152) f32 -> Wt (1152 x 768) bf16, 32x32 tiles, 256 threads
        __shared__ float tile[32][33];
        int tb = blk - 6144;
        int tbx = tb % 36;       // n tile
        int tby = tb / 36;       // k tile
        int tx = t & 31, ty = t >> 5;
#pragma unroll
        for (int r = 0; r < 4; ++r) {
            int row = ty + r * 8;  // k within tile
            tile[row][tx] = W[(tby * 32 + row) * 1152 + tbx * 32 + tx];
        }
        __syncthreads();
#pragma unroll
        for (int r = 0; r < 4; ++r) {
            int row = ty + r * 8;  // n within tile
            wtb[(size_t)(tbx * 32 + row) * 768 + tby * 32 + tx] = f2bf(tile[tx][row]);
        }
    } else {
        // sincos table: [512 pos][32 j] of (cos, sin) pairs
        int id = (blk - 7008) * 256 + t;   // 0..16383
        int pos = id >> 5, j = id & 31;
        float inv = powf(10000.0f, -2.0f * (float)j / 64.0f);
        float ang = (float)pos * inv;
        float s, c;
        sincosf(ang, &s, &c);
        scf[id * 2]     = c;
        scf[id * 2 + 1] = s;
    }
}

// ---------------- GEMM1: Wt(1152x768) x enc(8192x768)^T + bias, RoPE -> qk bf16 ----------------
// Operands swapped (A=Wt, B=enc) so acc register index walks the OUTPUT COLUMN (dd):
// RoPE pairs live in adjacent registers -> no shfl; packed 8B stores.
// qk layout: [bh=144][qk=2][s=512][d=64]
__global__ __launch_bounds__(256) void gemm1_rope(
    const short* __restrict__ A,    // 8192x768 bf16 row-major (enc)
    const short* __restrict__ Bt,   // 1152x768 bf16 row-major (W^T)
    const float* __restrict__ bias, // 1152
    const float* __restrict__ scf,  // 512 x 64 floats (c,s interleaved)
    short* __restrict__ qk)
{
    __shared__ __align__(16) short As[128 * 32];
    __shared__ __align__(16) short Bs[128 * 32];
    const int t = threadIdx.x;
    const int w = t >> 6, lane = t & 63;
    const int lr = lane & 15, quad = lane >> 4;
    const int wm = w >> 1, wn = w & 1;   // wm: n-side 64-range, wn: m-side 64-range
    const int m0 = blockIdx.y * 128;     // rows of enc (pos dim)
    const int n0 = blockIdx.x * 128;     // cols (tag*128 + qk*64 + dd)

    f32x4 acc[4][4] = {};

    const short* gA = A  + (size_t)(m0 + (t >> 2)) * 768 + (t & 3) * 8;
    const short* gB = Bt + (size_t)(n0 + (t >> 2)) * 768 + (t & 3) * 8;
    short* lA0 = &As[w * 512];
    short* lA1 = &As[2048 + w * 512];
    short* lB0 = &Bs[w * 512];
    short* lB1 = &Bs[2048 + w * 512];

    for (int kt = 0; kt < 24; ++kt) {
        __syncthreads();
        GLOAD16(gA,            lA0);
        GLOAD16(gA + 64 * 768, lA1);
        GLOAD16(gB,            lB0);
        GLOAD16(gB + 64 * 768, lB1);
        gA += 32; gB += 32;
        __syncthreads();

        s16x8 af[4], bw[4];
#pragma unroll
        for (int i = 0; i < 4; ++i)   // A-operand = Wt rows (n dim)
            af[i] = *(const s16x8*)&Bs[(wm * 64 + i * 16 + lr) * 32 + quad * 8];
#pragma unroll
        for (int j = 0; j < 4; ++j)   // B-operand = enc rows (m dim)
            bw[j] = *(const s16x8*)&As[(wn * 64 + j * 16 + lr) * 32 + quad * 8];
#pragma unroll
        for (int i = 0; i < 4; ++i)
#pragma unroll
            for (int j = 0; j < 4; ++j)
                acc[i][j] = __builtin_amdgcn_mfma_f32_16x16x32_bf16(af[i], bw[j], acc[i][j], 0, 0, 0);
    }

    // epilogue: acc[i][j][r] = D[n = n0+wm*64+i*16+quad*4+r][m = m0+wn*64+j*16+lr]
#pragma unroll
    for (int i = 0; i < 4; ++i) {
        const int colg0 = n0 + wm * 64 + i * 16 + quad * 4;   // 4-aligned
        const float4 bv = *(const float4*)&bias[colg0];
        const int tag = colg0 >> 7;
        const int qkf = (colg0 >> 6) & 1;
        const int dd0 = colg0 & 63;
        const int jj0 = dd0 >> 1;                              // even
        short* qbase = qk + ((size_t)tag * 2 + qkf) * 512 * 64 + dd0;
#pragma unroll
        for (int j = 0; j < 4; ++j) {
            const int rowg = m0 + wn * 64 + j * 16 + lr;
            const int bidx = rowg >> 9;
            const int pos  = rowg & 511;
            const float4 cs = *(const float4*)&scf[pos * 64 + jj0 * 2]; // {c0,s0,c1,s1}
            float x0 = acc[i][j][0] + bv.x;
            float x1 = acc[i][j][1] + bv.y;
            float x2 = acc[i][j][2] + bv.z;
            float x3 = acc[i][j][3] + bv.w;
            float o0 = x0 * cs.x - x1 * cs.y;
            float o1 = x1 * cs.x + x0 * cs.y;
            float o2 = x2 * cs.z - x3 * cs.w;
            float o3 = x3 * cs.z + x2 * cs.w;
            int2 st;
            st.x = (int)(f2bf_u(o0) & 0xFFFFu) | (int)(f2bf_u(o1) << 16);
            st.y = (int)(f2bf_u(o2) & 0xFFFFu) | (int)(f2bf_u(o3) << 16);
            *(int2*)&qbase[((size_t)bidx * 9 * 2 * 512 + pos) * 64] = st;
        }
    }
}

// ---------------- GEMM2: per (b,h): K(512x64) x Q(512x64)^T -> logits^T tile, masks, *0.125 ----------------
// Operands swapped (A=K, B=Q) so acc register index walks tg -> float4 stores (1KB/wave-instr).
__global__ __launch_bounds__(256) void gemm2_mask(
    const short* __restrict__ qk,
    const int* __restrict__ amask,   // (16,512) int32
    float* __restrict__ out)         // (16,9,512,512) f32
{
    __shared__ __align__(16) short Qs[128 * 64];
    __shared__ __align__(16) short Ks[128 * 64];
    const int t = threadIdx.x;
    const int w = t >> 6, lane = t & 63;
    const int lr = lane & 15, quad = lane >> 4;
    const int wm = w >> 1, wn = w & 1;   // wm: t-side, wn: s-side
    const int bh = blockIdx.z;
    const int bidx = bh / 9;
    const int s0 = blockIdx.y * 128;
    const int t0 = blockIdx.x * 128;

    const short* qbase = qk + (size_t)bh * 2 * 512 * 64;
    const short* kbase = qbase + 512 * 64;

    const int row = t >> 3, col8 = (t & 7) * 8;
#pragma unroll
    for (int p = 0; p < 4; ++p) {
        GLOAD16(qbase + (size_t)(s0 + p * 32 + row) * 64 + col8, &Qs[p * 2048 + w * 512]);
        GLOAD16(kbase + (size_t)(t0 + p * 32 + row) * 64 + col8, &Ks[p * 2048 + w * 512]);
    }
    __syncthreads();

    f32x4 acc[4][4] = {};
#pragma unroll
    for (int kk = 0; kk < 64; kk += 32) {
        s16x8 af[4], bw[4];
#pragma unroll
        for (int i = 0; i < 4; ++i)   // A-operand = K rows (t dim)
            af[i] = *(const s16x8*)&Ks[(wm * 64 + i * 16 + lr) * 64 + kk + quad * 8];
#pragma unroll
        for (int j = 0; j < 4; ++j)   // B-operand = Q rows (s dim)
            bw[j] = *(const s16x8*)&Qs[(wn * 64 + j * 16 + lr) * 64 + kk + quad * 8];
#pragma unroll
        for (int i = 0; i < 4; ++i)
#pragma unroll
            for (int j = 0; j < 4; ++j)
                acc[i][j] = __builtin_amdgcn_mfma_f32_16x16x32_bf16(af[i], bw[j], acc[i][j], 0, 0, 0);
    }

    // acc[i][j][r] = logits[s = s0+wn*64+j*16+lr][t = t0+wm*64+i*16+quad*4+r]
#pragma unroll
    for (int i = 0; i < 4; ++i) {
        const int tg0 = t0 + wm * 64 + i * 16 + quad * 4;   // 4-aligned
        const int4 am = *(const int4*)&amask[bidx * 512 + tg0];
        const float4 pad = make_float4((float)am.x, (float)am.y, (float)am.z, (float)am.w);
        const float4 mk = make_float4((1.0f - pad.x) * MASK_VALF, (1.0f - pad.y) * MASK_VALF,
                                      (1.0f - pad.z) * MASK_VALF, (1.0f - pad.w) * MASK_VALF);
#pragma unroll
        for (int j = 0; j < 4; ++j) {
            const int sg = s0 + wn * 64 + j * 16 + lr;
            float4 v;
            v.x = (acc[i][j][0] * pad.x - mk.x - (sg > tg0     ? MASK_VALF : 0.0f)) * 0.125f;
            v.y = (acc[i][j][1] * pad.y - mk.y - (sg > tg0 + 1 ? MASK_VALF : 0.0f)) * 0.125f;
            v.z = (acc[i][j][2] * pad.z - mk.z - (sg > tg0 + 2 ? MASK_VALF : 0.0f)) * 0.125f;
            v.w = (acc[i][j][3] * pad.w - mk.w - (sg > tg0 + 3 ? MASK_VALF : 0.0f)) * 0.125f;
            *(float4*)&out[((size_t)bh * 512 + sg) * 512 + tg0] = v;
        }
    }
}

extern "C" void kernel_launch(void* const* d_in, const int* in_sizes, int n_in,
                              void* d_out, int out_size, void* d_ws, size_t ws_size,
                              hipStream_t stream) {
    const float* enc   = (const float*)d_in[0];
    // d_in[1] = token_ids (unused by reference)
    const int*   amask = (const int*)d_in[2];
    const float* W     = (const float*)d_in[3];
    const float* bias  = (const float*)d_in[4];
    float* out = (float*)d_out;

    char* ws = (char*)d_ws;
    short* encb = (short*)(ws);                 // 8192*768*2   = 12,582,912 B
    short* wtb  = (short*)(ws + 12582912);      // 1152*768*2   =  1,769,472 B
    float* scf  = (float*)(ws + 14352384);      // 512*32*8     =    131,072 B
    short* qk   = (short*)(ws + 14483456);      // 144*2*512*64*2 = 18,874,368 B

    prep_all  <<<7072, 256, 0, stream>>>(enc, encb, W, wtb, scf);
    gemm1_rope<<<dim3(9, 64), 256, 0, stream>>>(encb, wtb, bias, scf, qk);
    gemm2_mask<<<dim3(4, 4, 144), 256, 0, stream>>>(qk, amask, out);
}